// Round 9
// baseline (156.422 us; speedup 1.0000x reference)
//
#include <hip/hip_runtime.h>
#include <hip/hip_bf16.h>

// out[m,o] = sum_k x[m,k] * (W[o,k]*scale) + bias[o]
// M=1024, K=4096, N=11008.
// R9: FUSED-W int8 GEMM. W int32 is read directly by the GEMM (low byte of
// each dword IS the int8); no wpack pre-pass. X f32 -> per-row i8 (xquant).
// GEMM: 128x128 tile, BKI=128, 256 thr (4 waves 2Mx2N, per-wave 64x64,
// acc=64 AGPR), dbuf 2x32KB LDS -> 2 blocks/CU, 688 blocks (~90% balance).
// A (Xq i8): global_load_lds, pre-swizzled source. B (W int32): 16 dwordx4
// -> byte-pack -> swizzled ds_write. One barrier/tile with full
// vmcnt(0)+lgkmcnt(0) drain (provably race-free). XCD-chunked swizzle:
// 688 = 8*86 bijective; the 8 M-sharers of each W-panel land on one XCD,
// so W streams from HBM once and L2 serves the 8x reuse.

#define M_TOT 1024
#define N_TOT 11008
#define K_TOT 4096
#define BM 128
#define BN 128
#define BKI 128                      // K-tile in i8 elems (= 128-B LDS rows)
#define NTI (K_TOT / BKI)            // 32 K-tiles
#define ABYTES_ (BM * BKI)           // 16 KB
#define BUFB    ((BM + BN) * BKI)    // 32 KB per buffer

typedef __attribute__((ext_vector_type(8))) short short8;
typedef __attribute__((ext_vector_type(4))) float f32x4;
typedef __attribute__((ext_vector_type(4))) int   i32x4;

__device__ __forceinline__ unsigned short f2bf(float f) {
    __hip_bfloat16 h = __float2bfloat16(f);
    return __builtin_bit_cast(unsigned short, h);
}

__device__ __forceinline__ void gload16(const void* g, void* l) {
    __builtin_amdgcn_global_load_lds(
        (const __attribute__((address_space(1))) unsigned int*)g,
        (__attribute__((address_space(3))) unsigned int*)l,
        16, 0, 0);
}

// ---------------- pre-pass: X f32 -> per-row i8 quant ----------------
__global__ __launch_bounds__(256)
void xquant_kernel(const float* __restrict__ X, int* __restrict__ Xq,
                   float* __restrict__ sx) {
    const int r = blockIdx.x;            // row 0..1023
    const int t = threadIdx.x;           // 0..255, 16 elems each
    const float* xr = X + (size_t)r * K_TOT + t * 16;
    f32x4 v[4];
    float amax = 0.0f;
#pragma unroll
    for (int j = 0; j < 4; ++j) {
        v[j] = *(const f32x4*)(xr + j * 4);
#pragma unroll
        for (int e = 0; e < 4; ++e) amax = fmaxf(amax, fabsf(v[j][e]));
    }
#pragma unroll
    for (int k = 1; k < 64; k <<= 1) amax = fmaxf(amax, __shfl_xor(amax, k));
    __shared__ float sm[4];
    if ((t & 63) == 0) sm[t >> 6] = amax;
    __syncthreads();
    amax = fmaxf(fmaxf(sm[0], sm[1]), fmaxf(sm[2], sm[3]));
    const float inv = (amax > 0.0f) ? (127.0f / amax) : 0.0f;
    if (t == 0) sx[r] = (amax > 0.0f) ? (amax / 127.0f) : 0.0f;
    i32x4 o;
#pragma unroll
    for (int j = 0; j < 4; ++j) {
        int q[4];
#pragma unroll
        for (int e = 0; e < 4; ++e) {
            int qi = (int)rintf(v[j][e] * inv);
            qi = qi > 127 ? 127 : (qi < -127 ? -127 : qi);
            q[e] = qi;
        }
        o[j] = (q[0] & 0xff) | ((q[1] & 0xff) << 8) | ((q[2] & 0xff) << 16) | (q[3] << 24);
    }
    *(i32x4*)(Xq + (size_t)r * (K_TOT / 4) + t * 4) = o;
}

// ---------------- main GEMM: fused W-dequant, i8 MFMA ----------------
__global__ __launch_bounds__(256, 2)
void gemm_fused_kernel(const char* __restrict__ Xq,   // [1024,4096] i8
                       const int* __restrict__ W,     // [11008,4096] int32 (i8-valued)
                       const float* __restrict__ sx,  // [1024] row scales
                       const float* __restrict__ scale,
                       const float* __restrict__ bias,
                       float* __restrict__ out) {     // [1024,11008]
    __shared__ __align__(16) unsigned char lds[2 * BUFB];   // 64 KB -> 2 blocks/CU

    const int tid  = threadIdx.x;     // 0..255
    const int lane = tid & 63;
    const int wid  = tid >> 6;        // 0..3
    const int wr   = wid >> 1;        // 0..1  (64-row strip)
    const int wc   = wid & 1;         // 0..1  (64-col strip)
    const int lr   = lane & 15;
    const int kb   = lane >> 4;       // 0..3

    // XCD-chunked bijective swizzle: 688 = 8 * 86.
    // wg enumerates (N-panel x, M-panel y) y-fastest; each XCD's contiguous
    // chunk of 86 holds ~10.75 complete x-groups -> the 8 M-sharers of a
    // W-panel co-reside on one XCD's L2.
    const int orig = blockIdx.x;                  // 0..687
    const int wg   = (orig & 7) * 86 + (orig >> 3);
    const int brow = (wg & 7) * BM;               // M-panel 0..7
    const int bcol = (wg >> 3) * BN;              // N-panel 0..85

    // ---- A staging (Xq i8 via gload_lds, pre-swizzled source) ----
    // per wave 32 rows, 4 chunks of 8 rows; lane l -> row l>>3, 16B slot
    // (l&7)^(l>>3) of the 128-B row (linear LDS dest).
    const int lds_row0 = wid * 32;
    const int s_row  = lds_row0 + (lane >> 3);
    const int s_colb = ((lane & 7) ^ (lane >> 3)) * 16;

    const char* asrc0 = Xq + (size_t)(brow + s_row) * K_TOT + s_colb;

    auto stageA = [&](int t, unsigned char* buf) {
        const size_t k0 = (size_t)t * BKI;
#pragma unroll
        for (int i = 0; i < 4; ++i)
            gload16(asrc0 + k0 + (size_t)i * 8 * K_TOT, buf + (lds_row0 + i * 8) * BKI);
    };

    // ---- B staging (W int32 -> regs -> pack -> swizzled ds_write) ----
    // per wave 32 rows x 512B int32 = 16 dwordx4; lane l covers row l>>3
    // (per 8-row quarter), int32 cols (l&7)*16 .. +15.
    const int* bW[4];
#pragma unroll
    for (int i = 0; i < 4; ++i)
        bW[i] = W + (size_t)(bcol + lds_row0 + i * 8 + (lane >> 3)) * K_TOT + (lane & 7) * 16;

    auto packw = [&](const int4 q[4]) {
        i32x4 o;
#pragma unroll
        for (int j = 0; j < 4; ++j)
            o[j] = (q[j].x & 0xff) | ((q[j].y & 0xff) << 8) |
                   ((q[j].z & 0xff) << 16) | (q[j].w << 24);
        return o;
    };
    auto bwrite = [&](unsigned char* buf, int i, i32x4 v) {
        *(i32x4*)(buf + ABYTES_ + (lds_row0 + i * 8 + (lane >> 3)) * BKI + s_colb) = v;
    };

    i32x4 acc[4][4];
#pragma unroll
    for (int m = 0; m < 4; ++m)
#pragma unroll
        for (int n = 0; n < 4; ++n)
#pragma unroll
            for (int i = 0; i < 4; ++i) acc[m][n][i] = 0;

    unsigned char* buf0 = lds;
    unsigned char* buf1 = lds + BUFB;

    // ---- prologue: tile 0 -> buf0 ----
    {
        int4 bq[4][4];
#pragma unroll
        for (int i = 0; i < 4; ++i)
#pragma unroll
            for (int j = 0; j < 4; ++j)
                bq[i][j] = *(const int4*)(bW[i] + j * 4);
        stageA(0, buf0);
#pragma unroll
        for (int i = 0; i < 4; ++i) bwrite(buf0, i, packw(bq[i]));
        asm volatile("s_waitcnt vmcnt(0) lgkmcnt(0)" ::: "memory");
        __builtin_amdgcn_s_barrier();
    }

    // one K-tile: reads cur, stages tile tn -> nxt. Single barrier at end
    // after a full vmcnt(0)+lgkmcnt(0) drain (A gload_lds + B ds_writes all
    // published; all ds_reads of cur retired -> WAR-safe).
    auto do_tile = [&](const unsigned char* cur, unsigned char* nxt, int tn) {
        // issue ALL next-tile loads up front (max latency cover)
        int4 bq[4][4];
#pragma unroll
        for (int i = 0; i < 4; ++i)
#pragma unroll
            for (int j = 0; j < 4; ++j)
                bq[i][j] = *(const int4*)(bW[i] + tn * BKI + j * 4);
        stageA(tn, nxt);
        __builtin_amdgcn_sched_barrier(0);   // pin loads above compute

        i32x4 a0[4], b0[4], a1[4], b1[4];
        // G0: kk=0 fragments
#pragma unroll
        for (int n = 0; n < 4; ++n) {
            int row = wc * 64 + n * 16 + lr;
            b0[n] = *(const i32x4*)(cur + ABYTES_ + row * BKI + ((kb * 16) ^ ((row & 7) << 4)));
        }
#pragma unroll
        for (int m = 0; m < 4; ++m) {
            int row = wr * 64 + m * 16 + lr;
            a0[m] = *(const i32x4*)(cur + row * BKI + ((kb * 16) ^ ((row & 7) << 4)));
        }
        // P0
        __builtin_amdgcn_s_setprio(1);
#pragma unroll
        for (int m = 0; m < 4; ++m)
#pragma unroll
            for (int n = 0; n < 4; ++n)
                acc[m][n] = __builtin_amdgcn_mfma_i32_16x16x64_i8(a0[m], b0[n], acc[m][n], 0, 0, 0);
        __builtin_amdgcn_s_setprio(0);
        __builtin_amdgcn_sched_barrier(0);   // keep packs below P0 (cover)

        // pack quarters 0,1 -> ds_write nxt
        bwrite(nxt, 0, packw(bq[0]));
        bwrite(nxt, 1, packw(bq[1]));

        // G1: kk=1 fragments
#pragma unroll
        for (int n = 0; n < 4; ++n) {
            int row = wc * 64 + n * 16 + lr;
            b1[n] = *(const i32x4*)(cur + ABYTES_ + row * BKI + ((64 + kb * 16) ^ ((row & 7) << 4)));
        }
#pragma unroll
        for (int m = 0; m < 4; ++m) {
            int row = wr * 64 + m * 16 + lr;
            a1[m] = *(const i32x4*)(cur + row * BKI + ((64 + kb * 16) ^ ((row & 7) << 4)));
        }
        // P1
        __builtin_amdgcn_s_setprio(1);
#pragma unroll
        for (int m = 0; m < 4; ++m)
#pragma unroll
            for (int n = 0; n < 4; ++n)
                acc[m][n] = __builtin_amdgcn_mfma_i32_16x16x64_i8(a1[m], b1[n], acc[m][n], 0, 0, 0);
        __builtin_amdgcn_s_setprio(0);

        // pack quarters 2,3
        bwrite(nxt, 2, packw(bq[2]));
        bwrite(nxt, 3, packw(bq[3]));

        asm volatile("s_waitcnt vmcnt(0) lgkmcnt(0)" ::: "memory");
        __builtin_amdgcn_s_barrier();
    };

    for (int t = 0; t < NTI; t += 2) {
        do_tile(buf0, buf1, t + 1);
        do_tile(buf1, buf0, (t + 2 < NTI) ? t + 2 : 0);   // wrap re-stage harmless
    }

    // epilogue: out = acc * (sx[row]*scale) + bias
    const float sw = scale[0];
    const int orow0 = brow + wr * 64;
    const int ocol0 = bcol + wc * 64;
    float bv[4];
#pragma unroll
    for (int n = 0; n < 4; ++n) bv[n] = bias[ocol0 + n * 16 + lr];
#pragma unroll
    for (int m = 0; m < 4; ++m) {
        f32x4 sx4 = *(const f32x4*)(sx + orow0 + m * 16 + kb * 4);
#pragma unroll
        for (int i = 0; i < 4; ++i) {
            int r = orow0 + m * 16 + kb * 4 + i;   // C/D: row=(lane>>4)*4+reg, col=lane&15
            size_t base = (size_t)r * N_TOT + ocol0;
            float fs = sx4[i] * sw;
#pragma unroll
            for (int n = 0; n < 4; ++n)
                out[base + n * 16 + lr] = (float)acc[m][n][i] * fs + bv[n];
        }
    }
}

// ---------------- fallback (round-1 fused bf16 kernel) if ws too small ----------------
__device__ __forceinline__ unsigned long long pack4(float a, float b, float c, float d) {
    return (unsigned long long)f2bf(a)
         | ((unsigned long long)f2bf(b) << 16)
         | ((unsigned long long)f2bf(c) << 32)
         | ((unsigned long long)f2bf(d) << 48);
}

#define FBM 128
#define FBN 128
#define FBK 64
#define FNT (K_TOT / FBK)

__global__ __launch_bounds__(256, 2)
void otf_linear_fused(const float* __restrict__ X, const int* __restrict__ W,
                      const float* __restrict__ scale, const float* __restrict__ bias,
                      float* __restrict__ out) {
    __shared__ __align__(16) unsigned char AsB[FBM * FBK * 2];
    __shared__ __align__(16) unsigned char BsB[FBN * FBK * 2];

    const int tid = threadIdx.x, lane = tid & 63, wid = tid >> 6;
    const int wr = wid >> 1, wc = wid & 1, lr = lane & 15, kb = lane >> 4;
    const int brow = blockIdx.y * FBM, bcol = blockIdx.x * FBN;
    const int srow = tid >> 4, sc4 = tid & 15;

    f32x4 areg[8];
    int4 breg[8];
    auto load_tiles = [&](int t) {
        const int k0 = t * FBK;
#pragma unroll
        for (int p = 0; p < 8; ++p) {
            int row = p * 16 + srow;
            areg[p] = *(const f32x4*)(&X[(size_t)(brow + row) * K_TOT + k0 + sc4 * 4]);
            breg[p] = *(const int4*)(&W[(size_t)(bcol + row) * K_TOT + k0 + sc4 * 4]);
        }
    };
    auto store_tiles = [&]() {
#pragma unroll
        for (int p = 0; p < 8; ++p) {
            int row = p * 16 + srow;
            int boff = (sc4 * 8) ^ ((row & 7) << 4);
            *(unsigned long long*)(&AsB[row * 128 + boff]) =
                pack4(areg[p][0], areg[p][1], areg[p][2], areg[p][3]);
            *(unsigned long long*)(&BsB[row * 128 + boff]) =
                pack4((float)breg[p].x, (float)breg[p].y, (float)breg[p].z, (float)breg[p].w);
        }
    };

    f32x4 acc[4][4];
#pragma unroll
    for (int m = 0; m < 4; ++m)
#pragma unroll
        for (int n = 0; n < 4; ++n)
#pragma unroll
            for (int i = 0; i < 4; ++i) acc[m][n][i] = 0.0f;

    load_tiles(0);
    for (int t = 0; t < FNT; ++t) {
        store_tiles();
        __syncthreads();
        if (t + 1 < FNT) load_tiles(t + 1);
#pragma unroll
        for (int kk = 0; kk < 2; ++kk) {
            short8 af[4], bfr[4];
#pragma unroll
            for (int m = 0; m < 4; ++m) {
                int row = wr * 64 + m * 16 + lr;
                int col = (kk * 64 + kb * 16) ^ ((row & 7) << 4);
                af[m] = *(const short8*)(&AsB[row * 128 + col]);
            }
#pragma unroll
            for (int n = 0; n < 4; ++n) {
                int row = wc * 64 + n * 16 + lr;
                int col = (kk * 64 + kb * 16) ^ ((row & 7) << 4);
                bfr[n] = *(const short8*)(&BsB[row * 128 + col]);
            }
#pragma unroll
            for (int m = 0; m < 4; ++m)
#pragma unroll
                for (int n = 0; n < 4; ++n)
                    acc[m][n] = __builtin_amdgcn_mfma_f32_16x16x32_bf16(af[m], bfr[n], acc[m][n], 0, 0, 0);
        }
        __syncthreads();
    }

    const float sc = scale[0];
    const int orow0 = brow + wr * 64, ocol0 = bcol + wc * 64;
    float bv[4];
#pragma unroll
    for (int n = 0; n < 4; ++n) bv[n] = bias[ocol0 + n * 16 + lr];
#pragma unroll
    for (int m = 0; m < 4; ++m)
#pragma unroll
        for (int i = 0; i < 4; ++i) {
            int r = orow0 + m * 16 + kb * 4 + i;
            size_t base = (size_t)r * N_TOT + ocol0;
#pragma unroll
            for (int n = 0; n < 4; ++n)
                out[base + n * 16 + lr] = acc[m][n][i] * sc + bv[n];
        }
}

extern "C" void kernel_launch(void* const* d_in, const int* in_sizes, int n_in,
                              void* d_out, int out_size, void* d_ws, size_t ws_size,
                              hipStream_t stream) {
    const float* x     = (const float*)d_in[0];
    const int*   w     = (const int*)d_in[1];
    const float* scale = (const float*)d_in[2];
    const float* bias  = (const float*)d_in[3];
    float* out = (float*)d_out;

    const size_t X_ELEMS = (size_t)M_TOT * K_TOT;   // 4,194,304
    const size_t need = X_ELEMS + M_TOT * sizeof(float);  // ~4.2 MB

    if (ws_size >= need) {
        char*  Xq = (char*)d_ws;
        float* sx = (float*)((char*)d_ws + X_ELEMS);
        xquant_kernel<<<M_TOT, 256, 0, stream>>>(x, (int*)Xq, sx);
        gemm_fused_kernel<<<dim3(688), 256, 0, stream>>>(Xq, w, sx, scale, bias, out);
    } else {
        otf_linear_fused<<<dim3(N_TOT / FBN, M_TOT / FBM), 256, 0, stream>>>(x, w, scale, bias, out);
    }
}

// Round 10
// 102.897 us; speedup vs baseline: 1.5202x; 1.5202x over previous
//
#include <hip/hip_runtime.h>
#include <hip/hip_bf16.h>

// out[m,o] = sum_k x[m,k] * (W[o,k]*scale) + bias[o]
// M=1024, K=4096, N=11008.
// R10 = R8 (best verified, 96.5us) + XCD-bijective grid swizzle + full-tile
// B latency cover.
// INT8 path: W int32 -> i8 pack (exact, wpack). X f32 -> per-row i8 quant.
// GEMM mfma_i32_16x16x64_i8, 256x256 tile, BKI=128, 512 thr (8 waves 2Mx4N),
// dbuf 2x64KB LDS, row-XOR swizzle (pre-swizzled global source + linear
// gload_lds dest + swizzled ds_read), 2 barriers/tile:
//   stageA(t+1)+stageB(t+1) -> vmcnt(8) -> BARRIER(visibility) ->
//   read/MFMA groups interleaved -> lgkmcnt(0) -> BARRIER(WAR).
// Swizzle: 172 blocks = 8 XCDs x (21|22); within an XCD chunk wg is
// consecutive with m = wg&3 fastest -> the 4 M-sharers of each Wq N-panel
// co-reside on one XCD's L2 (panel fetched once, reused 4x).

#define M_TOT 1024
#define N_TOT 11008
#define K_TOT 4096
#define BM 256
#define BN 256
#define BKI 128                       // K-tile in i8 elems (= 128-B rows)
#define NTI (K_TOT / BKI)             // 32 K-tiles (even)
#define ABYTES (BM * BKI)             // 32 KB
#define BUFB   ((BM + BN) * BKI)      // 64 KB per buffer

typedef __attribute__((ext_vector_type(8))) short short8;
typedef __attribute__((ext_vector_type(4))) float f32x4;
typedef __attribute__((ext_vector_type(4))) int   i32x4;

__device__ __forceinline__ unsigned short f2bf(float f) {
    __hip_bfloat16 h = __float2bfloat16(f);
    return __builtin_bit_cast(unsigned short, h);
}

__device__ __forceinline__ void gload16(const void* g, void* l) {
    __builtin_amdgcn_global_load_lds(
        (const __attribute__((address_space(1))) unsigned int*)g,
        (__attribute__((address_space(3))) unsigned int*)l,
        16, 0, 0);
}

// ---------------- pre-pass 1: W int32 -> i8 pack (exact, |v|<=127) ----------------
__global__ void wpack_kernel(const int* __restrict__ W, int* __restrict__ Wq, int n16) {
    int idx = blockIdx.x * blockDim.x + threadIdx.x;
    int stride = gridDim.x * blockDim.x;
    for (int i = idx; i < n16; i += stride) {
        const int4* p = (const int4*)W + (size_t)i * 4;
        i32x4 o;
#pragma unroll
        for (int j = 0; j < 4; ++j) {
            int4 v = p[j];
            o[j] = (v.x & 0xff) | ((v.y & 0xff) << 8) | ((v.z & 0xff) << 16) | (v.w << 24);
        }
        *(i32x4*)(Wq + (size_t)i * 4) = o;
    }
}

// ---------------- pre-pass 2: X f32 -> per-row i8 quant ----------------
__global__ __launch_bounds__(256)
void xquant_kernel(const float* __restrict__ X, int* __restrict__ Xq,
                   float* __restrict__ sx) {
    const int r = blockIdx.x;            // row 0..1023
    const int t = threadIdx.x;           // 0..255, 16 elems each
    const float* xr = X + (size_t)r * K_TOT + t * 16;
    f32x4 v[4];
    float amax = 0.0f;
#pragma unroll
    for (int j = 0; j < 4; ++j) {
        v[j] = *(const f32x4*)(xr + j * 4);
#pragma unroll
        for (int e = 0; e < 4; ++e) amax = fmaxf(amax, fabsf(v[j][e]));
    }
#pragma unroll
    for (int k = 1; k < 64; k <<= 1) amax = fmaxf(amax, __shfl_xor(amax, k));
    __shared__ float sm[4];
    if ((t & 63) == 0) sm[t >> 6] = amax;
    __syncthreads();
    amax = fmaxf(fmaxf(sm[0], sm[1]), fmaxf(sm[2], sm[3]));
    const float inv = (amax > 0.0f) ? (127.0f / amax) : 0.0f;
    if (t == 0) sx[r] = (amax > 0.0f) ? (amax / 127.0f) : 0.0f;
    i32x4 o;
#pragma unroll
    for (int j = 0; j < 4; ++j) {
        int q[4];
#pragma unroll
        for (int e = 0; e < 4; ++e) {
            int qi = (int)rintf(v[j][e] * inv);
            qi = qi > 127 ? 127 : (qi < -127 ? -127 : qi);
            q[e] = qi;
        }
        o[j] = (q[0] & 0xff) | ((q[1] & 0xff) << 8) | ((q[2] & 0xff) << 16) | (q[3] << 24);
    }
    *(i32x4*)(Xq + (size_t)r * (K_TOT / 4) + t * 4) = o;
}

// ---------------- main GEMM: i8 NT, 256^2, R8 schedule + swizzle ----------------
__global__ __launch_bounds__(512, 2)
void gemm_i8_kernel(const char* __restrict__ Xq,    // [1024,4096] i8
                    const char* __restrict__ Wq,    // [11008,4096] i8
                    const float* __restrict__ sx,   // [1024] row scales
                    const float* __restrict__ scale,
                    const float* __restrict__ bias,
                    float* __restrict__ out) {      // [1024,11008]
    __shared__ __align__(16) unsigned char lds[2 * BUFB];   // 128 KB

    const int tid  = threadIdx.x;
    const int lane = tid & 63;
    const int wid  = tid >> 6;        // 0..7
    const int wr   = wid >> 2;        // 0..1  (128-row half)
    const int wc   = wid & 3;         // 0..3  (64-col strip)
    const int lr   = lane & 15;
    const int kb   = lane >> 4;       // 0..3

    // XCD-bijective swizzle (m204): 172 blocks, 8 XCDs, q=21 r=4.
    // wg consecutive within an XCD chunk; m fastest -> 4 M-sharers of each
    // Wq N-panel land on the same XCD.
    const int orig = blockIdx.x;                 // 0..171
    const int xcd  = orig & 7;
    const int pos  = orig >> 3;
    const int wg   = (xcd < 4 ? xcd * 22 : 88 + (xcd - 4) * 21) + pos;
    const int brow = (wg & 3) * BM;              // M-panel 0..3
    const int bcol = (wg >> 2) * BN;             // N-panel 0..42

    // staging: per wave 32 rows A + 32 rows B (128 B each) = 4+4 gloads.
    // gload_lds dest linear; global source 16B-slot pre-swizzled:
    // src slot = (l&7) ^ (l>>3)  (row-in-chunk = l>>3).
    const int s_row  = wid * 32 + (lane >> 3);
    const int s_colb = (((lane & 7) ^ (lane >> 3)) * 16);   // bytes

    const char* asrc0 = Xq + (size_t)(brow + s_row) * K_TOT + s_colb;
    const char* bsrc0 = Wq + (size_t)(bcol + s_row) * K_TOT + s_colb;
    const int lds_row0 = wid * 32;

    auto stageA = [&](int t, unsigned char* buf) {
        const size_t k0 = (size_t)t * BKI;
#pragma unroll
        for (int i = 0; i < 4; ++i)
            gload16(asrc0 + k0 + (size_t)i * 8 * K_TOT, buf + (lds_row0 + i * 8) * BKI);
    };
    auto stageB = [&](int t, unsigned char* buf) {
        const size_t k0 = (size_t)t * BKI;
#pragma unroll
        for (int i = 0; i < 4; ++i)
            gload16(bsrc0 + k0 + (size_t)i * 8 * K_TOT, buf + ABYTES + (lds_row0 + i * 8) * BKI);
    };

    i32x4 acc[8][4];
#pragma unroll
    for (int m = 0; m < 8; ++m)
#pragma unroll
        for (int n = 0; n < 4; ++n)
#pragma unroll
            for (int i = 0; i < 4; ++i) acc[m][n][i] = 0;

    // one K-tile (K=128): reads cur, stages tile tn -> nxt.
    auto do_tile = [&](const unsigned char* cur, unsigned char* nxt, int tn) {
        stageA(tn, nxt);
        stageB(tn, nxt);                                   // full-tile cover for B too
        asm volatile("s_waitcnt vmcnt(8)" ::: "memory");   // retires A(t),B(t); t+1 in flight
        __builtin_amdgcn_s_barrier();                      // all waves' t-loads published
        __builtin_amdgcn_sched_barrier(0);

        i32x4 a0[4], a1[4], a2[4], a3[4], b0[4], b1[4];
        const int c0 = (kb * 16);          // kk=0 byte col (slot kb)
        const int c1 = (64 + kb * 16);     // kk=1 byte col (slot 4+kb)

        // G0: B(kk0) + A(kk0, m-half0)
#pragma unroll
        for (int n = 0; n < 4; ++n) {
            int row = wc * 64 + n * 16 + lr;
            b0[n] = *(const i32x4*)(cur + ABYTES + row * BKI + (c0 ^ ((row & 7) << 4)));
        }
#pragma unroll
        for (int m = 0; m < 4; ++m) {
            int row = wr * 128 + m * 16 + lr;
            a0[m] = *(const i32x4*)(cur + row * BKI + (c0 ^ ((row & 7) << 4)));
        }
        // G1: A(kk0, m-half1)
#pragma unroll
        for (int m = 0; m < 4; ++m) {
            int row = wr * 128 + 64 + m * 16 + lr;
            a1[m] = *(const i32x4*)(cur + row * BKI + (c0 ^ ((row & 7) << 4)));
        }

        // P0
        __builtin_amdgcn_s_setprio(1);
#pragma unroll
        for (int m = 0; m < 4; ++m)
#pragma unroll
            for (int n = 0; n < 4; ++n)
                acc[m][n] = __builtin_amdgcn_mfma_i32_16x16x64_i8(a0[m], b0[n], acc[m][n], 0, 0, 0);
        __builtin_amdgcn_s_setprio(0);

        // G2: B(kk1) + A(kk1, m-half0)
#pragma unroll
        for (int n = 0; n < 4; ++n) {
            int row = wc * 64 + n * 16 + lr;
            b1[n] = *(const i32x4*)(cur + ABYTES + row * BKI + (c1 ^ ((row & 7) << 4)));
        }
#pragma unroll
        for (int m = 0; m < 4; ++m) {
            int row = wr * 128 + m * 16 + lr;
            a2[m] = *(const i32x4*)(cur + row * BKI + (c1 ^ ((row & 7) << 4)));
        }

        // P1
        __builtin_amdgcn_s_setprio(1);
#pragma unroll
        for (int m = 0; m < 4; ++m)
#pragma unroll
            for (int n = 0; n < 4; ++n)
                acc[4 + m][n] = __builtin_amdgcn_mfma_i32_16x16x64_i8(a1[m], b0[n], acc[4 + m][n], 0, 0, 0);
        __builtin_amdgcn_s_setprio(0);

        // G3: A(kk1, m-half1)
#pragma unroll
        for (int m = 0; m < 4; ++m) {
            int row = wr * 128 + 64 + m * 16 + lr;
            a3[m] = *(const i32x4*)(cur + row * BKI + (c1 ^ ((row & 7) << 4)));
        }

        // P2
        __builtin_amdgcn_s_setprio(1);
#pragma unroll
        for (int m = 0; m < 4; ++m)
#pragma unroll
            for (int n = 0; n < 4; ++n)
                acc[m][n] = __builtin_amdgcn_mfma_i32_16x16x64_i8(a2[m], b1[n], acc[m][n], 0, 0, 0);
        __builtin_amdgcn_s_setprio(0);

        // P3
        __builtin_amdgcn_s_setprio(1);
#pragma unroll
        for (int m = 0; m < 4; ++m)
#pragma unroll
            for (int n = 0; n < 4; ++n)
                acc[4 + m][n] = __builtin_amdgcn_mfma_i32_16x16x64_i8(a3[m], b1[n], acc[4 + m][n], 0, 0, 0);
        __builtin_amdgcn_s_setprio(0);

        asm volatile("s_waitcnt lgkmcnt(0)" ::: "memory"); // all reads of cur retired
        __builtin_amdgcn_s_barrier();                      // WAR: cur re-staged next tile
    };

    unsigned char* buf0 = lds;
    unsigned char* buf1 = lds + BUFB;

    stageA(0, buf0);
    stageB(0, buf0);

    for (int t = 0; t < NTI; t += 2) {
        do_tile(buf0, buf1, t + 1);
        do_tile(buf1, buf0, (t + 2 < NTI) ? t + 2 : 0);    // wrap re-stage harmless
    }

    // epilogue: out = acc * (sx[row]*scale) + bias
    const float sw = scale[0];
    const int orow0 = brow + wr * 128;
    const int ocol0 = bcol + wc * 64;
    float bv[4];
#pragma unroll
    for (int n = 0; n < 4; ++n) bv[n] = bias[ocol0 + n * 16 + lr];
#pragma unroll
    for (int m = 0; m < 8; ++m) {
        // C/D: row=(lane>>4)*4+reg, col=lane&15; rows kb*4..kb*4+3 are 4-aligned
        f32x4 sx4 = *(const f32x4*)(sx + orow0 + m * 16 + kb * 4);
#pragma unroll
        for (int i = 0; i < 4; ++i) {
            int r = orow0 + m * 16 + kb * 4 + i;
            size_t base = (size_t)r * N_TOT + ocol0;
            float fs = sx4[i] * sw;
#pragma unroll
            for (int n = 0; n < 4; ++n)
                out[base + n * 16 + lr] = (float)acc[m][n][i] * fs + bv[n];
        }
    }
}

// ---------------- fallback (round-1 fused bf16 kernel) if ws too small ----------------
__device__ __forceinline__ unsigned long long pack4(float a, float b, float c, float d) {
    return (unsigned long long)f2bf(a)
         | ((unsigned long long)f2bf(b) << 16)
         | ((unsigned long long)f2bf(c) << 32)
         | ((unsigned long long)f2bf(d) << 48);
}

#define FBM 128
#define FBN 128
#define FBK 64
#define FNT (K_TOT / FBK)

__global__ __launch_bounds__(256, 2)
void otf_linear_fused(const float* __restrict__ X, const int* __restrict__ W,
                      const float* __restrict__ scale, const float* __restrict__ bias,
                      float* __restrict__ out) {
    __shared__ __align__(16) unsigned char AsB[FBM * FBK * 2];
    __shared__ __align__(16) unsigned char BsB[FBN * FBK * 2];

    const int tid = threadIdx.x, lane = tid & 63, wid = tid >> 6;
    const int wr = wid >> 1, wc = wid & 1, lr = lane & 15, kb = lane >> 4;
    const int brow = blockIdx.y * FBM, bcol = blockIdx.x * FBN;
    const int srow = tid >> 4, sc4 = tid & 15;

    f32x4 areg[8];
    int4 breg[8];
    auto load_tiles = [&](int t) {
        const int k0 = t * FBK;
#pragma unroll
        for (int p = 0; p < 8; ++p) {
            int row = p * 16 + srow;
            areg[p] = *(const f32x4*)(&X[(size_t)(brow + row) * K_TOT + k0 + sc4 * 4]);
            breg[p] = *(const int4*)(&W[(size_t)(bcol + row) * K_TOT + k0 + sc4 * 4]);
        }
    };
    auto store_tiles = [&]() {
#pragma unroll
        for (int p = 0; p < 8; ++p) {
            int row = p * 16 + srow;
            int boff = (sc4 * 8) ^ ((row & 7) << 4);
            *(unsigned long long*)(&AsB[row * 128 + boff]) =
                pack4(areg[p][0], areg[p][1], areg[p][2], areg[p][3]);
            *(unsigned long long*)(&BsB[row * 128 + boff]) =
                pack4((float)breg[p].x, (float)breg[p].y, (float)breg[p].z, (float)breg[p].w);
        }
    };

    f32x4 acc[4][4];
#pragma unroll
    for (int m = 0; m < 4; ++m)
#pragma unroll
        for (int n = 0; n < 4; ++n)
#pragma unroll
            for (int i = 0; i < 4; ++i) acc[m][n][i] = 0.0f;

    load_tiles(0);
    for (int t = 0; t < FNT; ++t) {
        store_tiles();
        __syncthreads();
        if (t + 1 < FNT) load_tiles(t + 1);
#pragma unroll
        for (int kk = 0; kk < 2; ++kk) {
            short8 af[4], bfr[4];
#pragma unroll
            for (int m = 0; m < 4; ++m) {
                int row = wr * 64 + m * 16 + lr;
                int col = (kk * 64 + kb * 16) ^ ((row & 7) << 4);
                af[m] = *(const short8*)(&AsB[row * 128 + col]);
            }
#pragma unroll
            for (int n = 0; n < 4; ++n) {
                int row = wc * 64 + n * 16 + lr;
                int col = (kk * 64 + kb * 16) ^ ((row & 7) << 4);
                bfr[n] = *(const short8*)(&BsB[row * 128 + col]);
            }
#pragma unroll
            for (int m = 0; m < 4; ++m)
#pragma unroll
                for (int n = 0; n < 4; ++n)
                    acc[m][n] = __builtin_amdgcn_mfma_f32_16x16x32_bf16(af[m], bfr[n], acc[m][n], 0, 0, 0);
        }
        __syncthreads();
    }

    const float sc = scale[0];
    const int orow0 = brow + wr * 64, ocol0 = bcol + wc * 64;
    float bv[4];
#pragma unroll
    for (int n = 0; n < 4; ++n) bv[n] = bias[ocol0 + n * 16 + lr];
#pragma unroll
    for (int m = 0; m < 4; ++m)
#pragma unroll
        for (int i = 0; i < 4; ++i) {
            int r = orow0 + m * 16 + kb * 4 + i;
            size_t base = (size_t)r * N_TOT + ocol0;
#pragma unroll
            for (int n = 0; n < 4; ++n)
                out[base + n * 16 + lr] = acc[m][n][i] * sc + bv[n];
        }
}

extern "C" void kernel_launch(void* const* d_in, const int* in_sizes, int n_in,
                              void* d_out, int out_size, void* d_ws, size_t ws_size,
                              hipStream_t stream) {
    const float* x     = (const float*)d_in[0];
    const int*   w     = (const int*)d_in[1];
    const float* scale = (const float*)d_in[2];
    const float* bias  = (const float*)d_in[3];
    float* out = (float*)d_out;

    const size_t W_ELEMS = (size_t)N_TOT * K_TOT;   // 45,088,768
    const size_t X_ELEMS = (size_t)M_TOT * K_TOT;   //  4,194,304
    const size_t need = W_ELEMS + X_ELEMS + M_TOT * sizeof(float);  // ~49.3 MB

    if (ws_size >= need) {
        char*  Wq = (char*)d_ws;
        char*  Xq = (char*)d_ws + W_ELEMS;
        float* sx = (float*)((char*)d_ws + W_ELEMS + X_ELEMS);
        wpack_kernel<<<2048, 256, 0, stream>>>(w, (int*)Wq, (int)(W_ELEMS / 16));
        xquant_kernel<<<M_TOT, 256, 0, stream>>>(x, (int*)Xq, sx);
        gemm_i8_kernel<<<dim3(172), 512, 0, stream>>>(Xq, Wq, sx, scale, bias, out);
    } else {
        otf_linear_fused<<<dim3(N_TOT / FBN, M_TOT / FBM), 256, 0, stream>>>(x, w, scale, bias, out);
    }
}